// Round 1
// baseline (385.739 us; speedup 1.0000x reference)
//
#include <hip/hip_runtime.h>

// LRU forward, MI355X/gfx950.
// Pipeline: prep (lambda/gamma/Bcat/Ccat/bf16-inputs) -> GEMM1 (Bu) ->
// chunked scan (32 chunks of 128, carry fix-up, in-place hs) -> GEMM2 (+skip).

typedef __bf16 bf16x8 __attribute__((ext_vector_type(8)));
typedef float floatx4 __attribute__((ext_vector_type(4)));

__device__ __forceinline__ unsigned short f2bf(float f) {
  unsigned u = __float_as_uint(f);
  u += 0x7fffu + ((u >> 16) & 1u);   // RNE; inputs are finite
  return (unsigned short)(u >> 16);
}
__device__ __forceinline__ float bf2f(unsigned short s) {
  return __uint_as_float(((unsigned)s) << 16);
}

// ---------------- prep kernels ----------------

__global__ void prep_params(const float* __restrict__ nu_log,
                            const float* __restrict__ theta_log,
                            float* __restrict__ lam,    // [2048] re|im
                            float* __restrict__ lamL,   // [2048] lambda^128 re|im
                            float* __restrict__ gamma)  // [1024]
{
  int h = blockIdx.x * 256 + threadIdx.x;   // exactly 1024
  float nu = expf(nu_log[h]);
  float th = expf(theta_log[h]);
  float r = expf(-nu);
  lam[h]        = r * cosf(th);
  lam[1024 + h] = r * sinf(th);
  float rL = expf(-128.0f * nu);
  lamL[h]        = rL * cosf(128.0f * th);
  lamL[1024 + h] = rL * sinf(128.0f * th);
  gamma[h] = sqrtf(1.0f - expf(-2.0f * nu) + 1e-5f);
}

__global__ void prep_B(const float* __restrict__ B_re, const float* __restrict__ B_im,
                       const float* __restrict__ gamma, unsigned short* __restrict__ Bcat)
{
  int tid = blockIdx.x * 256 + threadIdx.x;  // 2048*1024
  int n = tid >> 10;
  int d = tid & 1023;
  int h = n & 1023;
  float v = (n < 1024 ? B_re[h * 1024 + d] : B_im[h * 1024 + d]) * gamma[h];
  Bcat[tid] = f2bf(v);
}

__global__ void prep_C(const float* __restrict__ C_re, const float* __restrict__ C_im,
                       unsigned short* __restrict__ Ccat)
{
  int tid = blockIdx.x * 256 + threadIdx.x;  // 1024*2048
  int d = tid >> 11;
  int k = tid & 2047;
  float v = (k < 1024) ? C_re[d * 1024 + k] : -C_im[d * 1024 + (k - 1024)];
  Ccat[tid] = f2bf(v);
}

__global__ void conv_inputs(const float* __restrict__ in, unsigned short* __restrict__ outb)
{
  int tid = blockIdx.x * 256 + threadIdx.x;  // 16.7M/4
  float4 v = ((const float4*)in)[tid];
  unsigned lo = (unsigned)f2bf(v.x) | ((unsigned)f2bf(v.y) << 16);
  unsigned hi = (unsigned)f2bf(v.z) | ((unsigned)f2bf(v.w) << 16);
  ((uint2*)outb)[tid] = make_uint2(lo, hi);
}

// ---------------- GEMM (A: [M,K] k-contig, Bt: [N,K] k-contig) ----------------
// 128x128 tile, BK=32, 4 waves (2x2), 16x mfma_f32_16x16x32_bf16 per wave/iter.
// LDS layout: row r (64B) holds its four 16B k-chunks at positions p, where
// position p stores logical chunk p ^ ((r>>1)&3)  (bank-spread, keeps the
// global_load_lds lane->base+i*16 contiguity requirement).

template <int EPI>
__global__ __launch_bounds__(256) void gemm_bt_kernel(
    const unsigned short* __restrict__ A,
    const unsigned short* __restrict__ Bt,
    void* __restrict__ Cout,
    int M, int N, int K,
    const float* __restrict__ skip_in,
    const float* __restrict__ skip_w)
{
  __shared__ unsigned short As[128 * 32];
  __shared__ unsigned short Bs[128 * 32];

  const int tid  = threadIdx.x;
  const int lane = tid & 63;
  const int wave = tid >> 6;
  const int wm = wave >> 1;
  const int wn = wave & 1;
  const int m0 = blockIdx.y * 128;
  const int n0 = blockIdx.x * 128;

  const int ldr = lane >> 2;   // 0..15: row within a 16-row staging group
  const int pos = lane & 3;    // 16B chunk position within the 64B row
  const int lm  = lane & 15;   // fragment row (A: m, B: n)
  const int q   = lane >> 4;   // fragment k-chunk (k = q*8 + j)

  floatx4 acc[4][4];
#pragma unroll
  for (int i = 0; i < 4; ++i)
#pragma unroll
    for (int j = 0; j < 4; ++j)
      acc[i][j] = (floatx4){0.f, 0.f, 0.f, 0.f};

  for (int kt = 0; kt < K; kt += 32) {
    __syncthreads();   // previous iter's ds_reads done before overwrite
#pragma unroll
    for (int half = 0; half < 2; ++half) {
      const int r  = wave * 32 + half * 16 + ldr;     // row within tile, 0..127
      const int ca = pos ^ ((r >> 1) & 3);            // logical chunk at this pos
      const unsigned short* ga = A  + (size_t)(m0 + r) * K + kt + ca * 8;
      const unsigned short* gb = Bt + (size_t)(n0 + r) * K + kt + ca * 8;
      __builtin_amdgcn_global_load_lds(
          (const __attribute__((address_space(1))) void*)ga,
          (__attribute__((address_space(3))) void*)&As[r * 32 + pos * 8], 16, 0, 0);
      __builtin_amdgcn_global_load_lds(
          (const __attribute__((address_space(1))) void*)gb,
          (__attribute__((address_space(3))) void*)&Bs[r * 32 + pos * 8], 16, 0, 0);
    }
    __syncthreads();   // vmcnt(0) drained before barrier => LDS ready

    bf16x8 afrag[4], bfrag[4];
#pragma unroll
    for (int i = 0; i < 4; ++i) {
      const int r = wm * 64 + i * 16 + lm;
      afrag[i] = *reinterpret_cast<const bf16x8*>(&As[r * 32 + (q ^ ((r >> 1) & 3)) * 8]);
    }
#pragma unroll
    for (int j = 0; j < 4; ++j) {
      const int r = wn * 64 + j * 16 + lm;
      bfrag[j] = *reinterpret_cast<const bf16x8*>(&Bs[r * 32 + (q ^ ((r >> 1) & 3)) * 8]);
    }
#pragma unroll
    for (int i = 0; i < 4; ++i)
#pragma unroll
      for (int j = 0; j < 4; ++j)
        acc[i][j] = __builtin_amdgcn_mfma_f32_16x16x32_bf16(afrag[i], bfrag[j], acc[i][j], 0, 0, 0);
  }

  // Epilogue. C/D layout: col = lane&15, row = (lane>>4)*4 + reg.
#pragma unroll
  for (int i = 0; i < 4; ++i) {
#pragma unroll
    for (int j = 0; j < 4; ++j) {
      const int row0 = m0 + wm * 64 + i * 16 + q * 4;
      const int col  = n0 + wn * 64 + j * 16 + lm;
#pragma unroll
      for (int r = 0; r < 4; ++r) {
        const size_t idx = (size_t)(row0 + r) * N + col;
        if (EPI == 0) {
          ((unsigned short*)Cout)[idx] = f2bf(acc[i][j][r]);
        } else {
          ((float*)Cout)[idx] = acc[i][j][r] + skip_in[idx] * skip_w[col];
        }
      }
    }
  }
}

// ---------------- chunked scan over T ----------------
// Bu layout: [(b*4096 + t) * 2048 + h] re-plane (h<1024), +1024 im-plane.
// tid = b*32768 + c*1024 + h  (B=4, C=32 chunks of L=128, H=1024)

__global__ void scan_finals(const unsigned short* __restrict__ Bu,
                            const float* __restrict__ lam,
                            float2* __restrict__ finals)
{
  int tid = blockIdx.x * 256 + threadIdx.x;
  int h = tid & 1023, c = (tid >> 10) & 31, b = tid >> 15;
  float lre = lam[h], lim = lam[1024 + h];
  const unsigned short* p = Bu + ((size_t)(b * 4096 + c * 128) * 2048) + h;
  float yre = 0.f, yim = 0.f;
#pragma unroll 4
  for (int t = 0; t < 128; ++t) {
    float ure = bf2f(p[0]);
    float uim = bf2f(p[1024]);
    float nre = fmaf(lre, yre, fmaf(-lim, yim, ure));
    float nim = fmaf(lre, yim, fmaf(lim, yre, uim));
    yre = nre; yim = nim;
    p += 2048;
  }
  finals[tid] = make_float2(yre, yim);
}

__global__ void scan_carries(const float2* __restrict__ finals,
                             const float* __restrict__ lamL,
                             float2* __restrict__ carry)
{
  int tid = blockIdx.x * 256 + threadIdx.x;  // 4096 = B*H
  int h = tid & 1023, b = tid >> 10;
  float Lre = lamL[h], Lim = lamL[1024 + h];
  float Hre = 0.f, Him = 0.f;
  for (int c = 0; c < 32; ++c) {
    size_t i = ((size_t)(b * 32 + c) << 10) + h;
    carry[i] = make_float2(Hre, Him);   // carry INTO chunk c (H_{c-1})
    float2 f = finals[i];
    float nre = fmaf(Lre, Hre, fmaf(-Lim, Him, f.x));
    float nim = fmaf(Lre, Him, fmaf(Lim, Hre, f.y));
    Hre = nre; Him = nim;
  }
}

__global__ void scan_apply(const float* __restrict__ lam,
                           const float2* __restrict__ carry,
                           unsigned short* __restrict__ Bu)  // in-place -> hs
{
  int tid = blockIdx.x * 256 + threadIdx.x;
  int h = tid & 1023, c = (tid >> 10) & 31, b = tid >> 15;
  float lre = lam[h], lim = lam[1024 + h];
  float2 cv = carry[tid];
  float yre = cv.x, yim = cv.y;
  unsigned short* p = Bu + ((size_t)(b * 4096 + c * 128) * 2048) + h;
#pragma unroll 4
  for (int t = 0; t < 128; ++t) {
    float ure = bf2f(p[0]);
    float uim = bf2f(p[1024]);
    float nre = fmaf(lre, yre, fmaf(-lim, yim, ure));
    float nim = fmaf(lre, yim, fmaf(lim, yre, uim));
    yre = nre; yim = nim;
    p[0]    = f2bf(yre);
    p[1024] = f2bf(yim);
    p += 2048;
  }
}

// ---------------- launch ----------------

extern "C" void kernel_launch(void* const* d_in, const int* in_sizes, int n_in,
                              void* d_out, int out_size, void* d_ws, size_t ws_size,
                              hipStream_t stream)
{
  const float* inputs    = (const float*)d_in[0];
  const float* nu_log    = (const float*)d_in[1];
  const float* theta_log = (const float*)d_in[2];
  const float* B_re      = (const float*)d_in[3];
  const float* B_im      = (const float*)d_in[4];
  const float* C_re      = (const float*)d_in[5];
  const float* C_im      = (const float*)d_in[6];
  const float* D_skip    = (const float*)d_in[7];
  float* out = (float*)d_out;

  char* ws = (char*)d_ws;
  float* lam   = (float*)ws;            // 2048 f32
  float* lamL  = lam + 2048;            // 2048 f32
  float* gamma = lamL + 2048;           // 1024 f32
  unsigned short* inp_bf = (unsigned short*)(ws + (1 << 16));       // 16384x1024 bf16
  unsigned short* Bcat   = inp_bf + (size_t)16384 * 1024;           // 2048x1024
  unsigned short* Ccat   = Bcat   + (size_t)2048 * 1024;            // 1024x2048
  unsigned short* Bu     = Ccat   + (size_t)1024 * 2048;            // 16384x2048 (re|im), becomes hs in place
  float2* finals = (float2*)(Bu + (size_t)16384 * 2048);            // 131072
  float2* carry  = finals + 131072;                                 // 131072
  // total ws use ~111 MB

  prep_params<<<4,    256, 0, stream>>>(nu_log, theta_log, lam, lamL, gamma);
  prep_B     <<<8192, 256, 0, stream>>>(B_re, B_im, gamma, Bcat);
  prep_C     <<<8192, 256, 0, stream>>>(C_re, C_im, Ccat);
  conv_inputs<<<16384,256, 0, stream>>>(inputs, inp_bf);

  // GEMM1: Bu[bt, n] = inputs @ Bcat^T   (M=16384, N=2048, K=1024)
  gemm_bt_kernel<0><<<dim3(16, 128), 256, 0, stream>>>(
      inp_bf, Bcat, Bu, 16384, 2048, 1024, nullptr, nullptr);

  scan_finals <<<512, 256, 0, stream>>>(Bu, lam, finals);
  scan_carries<<<16,  256, 0, stream>>>(finals, lamL, carry);
  scan_apply  <<<512, 256, 0, stream>>>(lam, carry, Bu);   // Bu -> hs in place

  // GEMM2: out[bt, d] = hs @ Ccat^T + inputs * D_skip  (M=16384, N=1024, K=2048)
  gemm_bt_kernel<1><<<dim3(8, 128), 256, 0, stream>>>(
      Bu, Ccat, out, 16384, 1024, 2048, inputs, D_skip);
}

// Round 2
// 382.369 us; speedup vs baseline: 1.0088x; 1.0088x over previous
//
#include <hip/hip_runtime.h>

// LRU forward, MI355X/gfx950.
// Pipeline: prep (lambda/gamma/Bcat/Ccat/bf16-inputs) -> GEMM1 (Bu) ->
// chunked scan (32 chunks of 128, carry fix-up, in-place hs) -> GEMM2 (+skip).
// R2: 1D-grid XCD-compact swizzle in the GEMMs (xcd=id&7 owns a 16-Mtile
// stripe x all N-tiles) to fix the 299MB over-fetch measured in R1.

typedef __bf16 bf16x8 __attribute__((ext_vector_type(8)));
typedef float floatx4 __attribute__((ext_vector_type(4)));

__device__ __forceinline__ unsigned short f2bf(float f) {
  unsigned u = __float_as_uint(f);
  u += 0x7fffu + ((u >> 16) & 1u);   // RNE; inputs are finite
  return (unsigned short)(u >> 16);
}
__device__ __forceinline__ float bf2f(unsigned short s) {
  return __uint_as_float(((unsigned)s) << 16);
}

// ---------------- prep kernels ----------------

__global__ void prep_params(const float* __restrict__ nu_log,
                            const float* __restrict__ theta_log,
                            float* __restrict__ lam,    // [2048] re|im
                            float* __restrict__ lamL,   // [2048] lambda^128 re|im
                            float* __restrict__ gamma)  // [1024]
{
  int h = blockIdx.x * 256 + threadIdx.x;   // exactly 1024
  float nu = expf(nu_log[h]);
  float th = expf(theta_log[h]);
  float r = expf(-nu);
  lam[h]        = r * cosf(th);
  lam[1024 + h] = r * sinf(th);
  float rL = expf(-128.0f * nu);
  lamL[h]        = rL * cosf(128.0f * th);
  lamL[1024 + h] = rL * sinf(128.0f * th);
  gamma[h] = sqrtf(1.0f - expf(-2.0f * nu) + 1e-5f);
}

__global__ void prep_B(const float* __restrict__ B_re, const float* __restrict__ B_im,
                       const float* __restrict__ gamma, unsigned short* __restrict__ Bcat)
{
  int tid = blockIdx.x * 256 + threadIdx.x;  // 2048*1024
  int n = tid >> 10;
  int d = tid & 1023;
  int h = n & 1023;
  float v = (n < 1024 ? B_re[h * 1024 + d] : B_im[h * 1024 + d]) * gamma[h];
  Bcat[tid] = f2bf(v);
}

__global__ void prep_C(const float* __restrict__ C_re, const float* __restrict__ C_im,
                       unsigned short* __restrict__ Ccat)
{
  int tid = blockIdx.x * 256 + threadIdx.x;  // 1024*2048
  int d = tid >> 11;
  int k = tid & 2047;
  float v = (k < 1024) ? C_re[d * 1024 + k] : -C_im[d * 1024 + (k - 1024)];
  Ccat[tid] = f2bf(v);
}

__global__ void conv_inputs(const float* __restrict__ in, unsigned short* __restrict__ outb)
{
  int tid = blockIdx.x * 256 + threadIdx.x;  // 16.7M/4
  float4 v = ((const float4*)in)[tid];
  unsigned lo = (unsigned)f2bf(v.x) | ((unsigned)f2bf(v.y) << 16);
  unsigned hi = (unsigned)f2bf(v.z) | ((unsigned)f2bf(v.w) << 16);
  ((uint2*)outb)[tid] = make_uint2(lo, hi);
}

// ---------------- GEMM (A: [M,K] k-contig, Bt: [N,K] k-contig) ----------------
// 128x128 tile, BK=32, 4 waves (2x2), 16x mfma_f32_16x16x32_bf16 per wave/iter.
// 1D grid of (M/128)*(N/128) blocks. XCD-compact swizzle: assuming HW assigns
// block id -> XCD id%8, xcd owns m-tiles [xcd*16, xcd*16+16) x all n-tiles,
// m-fastest (resident ~96 blocks/XCD span 16m x ~6n -> A k-slices hit 6x,
// B k-slices 16x from the 4MB per-XCD L2).
// LDS: row r (64B) holds its four 16B k-chunks at positions p storing logical
// chunk p ^ ((r>>1)&3) (bank spread; keeps global_load_lds lane contiguity).

template <int EPI>
__global__ __launch_bounds__(256) void gemm_bt_kernel(
    const unsigned short* __restrict__ A,
    const unsigned short* __restrict__ Bt,
    void* __restrict__ Cout,
    int M, int N, int K,
    const float* __restrict__ skip_in,
    const float* __restrict__ skip_w)
{
  __shared__ unsigned short As[128 * 32];
  __shared__ unsigned short Bs[128 * 32];

  const int tid  = threadIdx.x;
  const int lane = tid & 63;
  const int wave = tid >> 6;
  const int wm = wave >> 1;
  const int wn = wave & 1;

  // XCD-compact tile assignment (M/128 == 128 assumed: 8 XCDs x 16 m-tiles)
  const int flat    = blockIdx.x;
  const int xcd     = flat & 7;
  const int local   = flat >> 3;
  const int m_tile  = xcd * 16 + (local & 15);
  const int n_tile  = local >> 4;
  const int m0 = m_tile * 128;
  const int n0 = n_tile * 128;

  const int ldr = lane >> 2;   // 0..15: row within a 16-row staging group
  const int pos = lane & 3;    // 16B chunk position within the 64B row
  const int lm  = lane & 15;   // fragment row (A: m, B: n)
  const int q   = lane >> 4;   // fragment k-chunk (k = q*8 + j)

  floatx4 acc[4][4];
#pragma unroll
  for (int i = 0; i < 4; ++i)
#pragma unroll
    for (int j = 0; j < 4; ++j)
      acc[i][j] = (floatx4){0.f, 0.f, 0.f, 0.f};

  for (int kt = 0; kt < K; kt += 32) {
    __syncthreads();   // previous iter's ds_reads done before overwrite
#pragma unroll
    for (int half = 0; half < 2; ++half) {
      const int r  = wave * 32 + half * 16 + ldr;     // row within tile, 0..127
      const int ca = pos ^ ((r >> 1) & 3);            // logical chunk at this pos
      const unsigned short* ga = A  + (size_t)(m0 + r) * K + kt + ca * 8;
      const unsigned short* gb = Bt + (size_t)(n0 + r) * K + kt + ca * 8;
      __builtin_amdgcn_global_load_lds(
          (const __attribute__((address_space(1))) void*)ga,
          (__attribute__((address_space(3))) void*)&As[r * 32 + pos * 8], 16, 0, 0);
      __builtin_amdgcn_global_load_lds(
          (const __attribute__((address_space(1))) void*)gb,
          (__attribute__((address_space(3))) void*)&Bs[r * 32 + pos * 8], 16, 0, 0);
    }
    __syncthreads();   // vmcnt(0) drained before barrier => LDS ready

    bf16x8 afrag[4], bfrag[4];
#pragma unroll
    for (int i = 0; i < 4; ++i) {
      const int r = wm * 64 + i * 16 + lm;
      afrag[i] = *reinterpret_cast<const bf16x8*>(&As[r * 32 + (q ^ ((r >> 1) & 3)) * 8]);
    }
#pragma unroll
    for (int j = 0; j < 4; ++j) {
      const int r = wn * 64 + j * 16 + lm;
      bfrag[j] = *reinterpret_cast<const bf16x8*>(&Bs[r * 32 + (q ^ ((r >> 1) & 3)) * 8]);
    }
#pragma unroll
    for (int i = 0; i < 4; ++i)
#pragma unroll
      for (int j = 0; j < 4; ++j)
        acc[i][j] = __builtin_amdgcn_mfma_f32_16x16x32_bf16(afrag[i], bfrag[j], acc[i][j], 0, 0, 0);
  }

  // Epilogue. C/D layout: col = lane&15, row = (lane>>4)*4 + reg.
#pragma unroll
  for (int i = 0; i < 4; ++i) {
#pragma unroll
    for (int j = 0; j < 4; ++j) {
      const int row0 = m0 + wm * 64 + i * 16 + q * 4;
      const int col  = n0 + wn * 64 + j * 16 + lm;
#pragma unroll
      for (int r = 0; r < 4; ++r) {
        const size_t idx = (size_t)(row0 + r) * N + col;
        if (EPI == 0) {
          ((unsigned short*)Cout)[idx] = f2bf(acc[i][j][r]);
        } else {
          ((float*)Cout)[idx] = acc[i][j][r] + skip_in[idx] * skip_w[col];
        }
      }
    }
  }
}

// ---------------- chunked scan over T ----------------
// Bu layout: [(b*4096 + t) * 2048 + h] re-plane (h<1024), +1024 im-plane.
// tid = b*32768 + c*1024 + h  (B=4, C=32 chunks of L=128, H=1024)

__global__ void scan_finals(const unsigned short* __restrict__ Bu,
                            const float* __restrict__ lam,
                            float2* __restrict__ finals)
{
  int tid = blockIdx.x * 256 + threadIdx.x;
  int h = tid & 1023, c = (tid >> 10) & 31, b = tid >> 15;
  float lre = lam[h], lim = lam[1024 + h];
  const unsigned short* p = Bu + ((size_t)(b * 4096 + c * 128) * 2048) + h;
  float yre = 0.f, yim = 0.f;
#pragma unroll 4
  for (int t = 0; t < 128; ++t) {
    float ure = bf2f(p[0]);
    float uim = bf2f(p[1024]);
    float nre = fmaf(lre, yre, fmaf(-lim, yim, ure));
    float nim = fmaf(lre, yim, fmaf(lim, yre, uim));
    yre = nre; yim = nim;
    p += 2048;
  }
  finals[tid] = make_float2(yre, yim);
}

__global__ void scan_carries(const float2* __restrict__ finals,
                             const float* __restrict__ lamL,
                             float2* __restrict__ carry)
{
  int tid = blockIdx.x * 256 + threadIdx.x;  // 4096 = B*H
  int h = tid & 1023, b = tid >> 10;
  float Lre = lamL[h], Lim = lamL[1024 + h];
  float Hre = 0.f, Him = 0.f;
  for (int c = 0; c < 32; ++c) {
    size_t i = ((size_t)(b * 32 + c) << 10) + h;
    carry[i] = make_float2(Hre, Him);   // carry INTO chunk c (H_{c-1})
    float2 f = finals[i];
    float nre = fmaf(Lre, Hre, fmaf(-Lim, Him, f.x));
    float nim = fmaf(Lre, Him, fmaf(Lim, Hre, f.y));
    Hre = nre; Him = nim;
  }
}

__global__ void scan_apply(const float* __restrict__ lam,
                           const float2* __restrict__ carry,
                           unsigned short* __restrict__ Bu)  // in-place -> hs
{
  int tid = blockIdx.x * 256 + threadIdx.x;
  int h = tid & 1023, c = (tid >> 10) & 31, b = tid >> 15;
  float lre = lam[h], lim = lam[1024 + h];
  float2 cv = carry[tid];
  float yre = cv.x, yim = cv.y;
  unsigned short* p = Bu + ((size_t)(b * 4096 + c * 128) * 2048) + h;
#pragma unroll 4
  for (int t = 0; t < 128; ++t) {
    float ure = bf2f(p[0]);
    float uim = bf2f(p[1024]);
    float nre = fmaf(lre, yre, fmaf(-lim, yim, ure));
    float nim = fmaf(lre, yim, fmaf(lim, yre, uim));
    yre = nre; yim = nim;
    p[0]    = f2bf(yre);
    p[1024] = f2bf(yim);
    p += 2048;
  }
}

// ---------------- launch ----------------

extern "C" void kernel_launch(void* const* d_in, const int* in_sizes, int n_in,
                              void* d_out, int out_size, void* d_ws, size_t ws_size,
                              hipStream_t stream)
{
  const float* inputs    = (const float*)d_in[0];
  const float* nu_log    = (const float*)d_in[1];
  const float* theta_log = (const float*)d_in[2];
  const float* B_re      = (const float*)d_in[3];
  const float* B_im      = (const float*)d_in[4];
  const float* C_re      = (const float*)d_in[5];
  const float* C_im      = (const float*)d_in[6];
  const float* D_skip    = (const float*)d_in[7];
  float* out = (float*)d_out;

  char* ws = (char*)d_ws;
  float* lam   = (float*)ws;            // 2048 f32
  float* lamL  = lam + 2048;            // 2048 f32
  float* gamma = lamL + 2048;           // 1024 f32
  unsigned short* inp_bf = (unsigned short*)(ws + (1 << 16));       // 16384x1024 bf16
  unsigned short* Bcat   = inp_bf + (size_t)16384 * 1024;           // 2048x1024
  unsigned short* Ccat   = Bcat   + (size_t)2048 * 1024;            // 1024x2048
  unsigned short* Bu     = Ccat   + (size_t)1024 * 2048;            // 16384x2048 (re|im), becomes hs in place
  float2* finals = (float2*)(Bu + (size_t)16384 * 2048);            // 131072
  float2* carry  = finals + 131072;                                 // 131072
  // total ws use ~111 MB

  prep_params<<<4,    256, 0, stream>>>(nu_log, theta_log, lam, lamL, gamma);
  prep_B     <<<8192, 256, 0, stream>>>(B_re, B_im, gamma, Bcat);
  prep_C     <<<8192, 256, 0, stream>>>(C_re, C_im, Ccat);
  conv_inputs<<<16384,256, 0, stream>>>(inputs, inp_bf);

  // GEMM1: Bu[bt, n] = inputs @ Bcat^T   (M=16384, N=2048, K=1024)
  gemm_bt_kernel<0><<<2048, 256, 0, stream>>>(
      inp_bf, Bcat, Bu, 16384, 2048, 1024, nullptr, nullptr);

  scan_finals <<<512, 256, 0, stream>>>(Bu, lam, finals);
  scan_carries<<<16,  256, 0, stream>>>(finals, lamL, carry);
  scan_apply  <<<512, 256, 0, stream>>>(lam, carry, Bu);   // Bu -> hs in place

  // GEMM2: out[bt, d] = hs @ Ccat^T + inputs * D_skip  (M=16384, N=1024, K=2048)
  gemm_bt_kernel<1><<<1024, 256, 0, stream>>>(
      Bu, Ccat, out, 16384, 1024, 2048, inputs, D_skip);
}

// Round 3
// 364.234 us; speedup vs baseline: 1.0590x; 1.0498x over previous
//
#include <hip/hip_runtime.h>

// LRU forward, MI355X/gfx950.
// Pipeline: prep (lambda/gamma/Bcat/Ccat/bf16-inputs) -> GEMM1 (Bu) ->
// chunked scan (32 chunks of 128, carry fix-up, in-place hs) -> GEMM2 (+skip).
// R2: 1D-grid XCD-compact swizzle (FETCH 299->115MB, confirmed id%8 mapping).
// R3: double-buffered LDS software pipeline, 1 barrier/iter, next-tile
// global_load_lds issued before compute so the pre-barrier vmcnt(0) drain
// overlaps the ds_read+MFMA phase (R2 was latency-bound: ~1130cyc/blk-iter
// vs 385cyc LDS floor, loads drained cold at the barrier).

typedef __bf16 bf16x8 __attribute__((ext_vector_type(8)));
typedef float floatx4 __attribute__((ext_vector_type(4)));

__device__ __forceinline__ unsigned short f2bf(float f) {
  unsigned u = __float_as_uint(f);
  u += 0x7fffu + ((u >> 16) & 1u);   // RNE; inputs are finite
  return (unsigned short)(u >> 16);
}
__device__ __forceinline__ float bf2f(unsigned short s) {
  return __uint_as_float(((unsigned)s) << 16);
}

// ---------------- prep kernels ----------------

__global__ void prep_params(const float* __restrict__ nu_log,
                            const float* __restrict__ theta_log,
                            float* __restrict__ lam,    // [2048] re|im
                            float* __restrict__ lamL,   // [2048] lambda^128 re|im
                            float* __restrict__ gamma)  // [1024]
{
  int h = blockIdx.x * 256 + threadIdx.x;   // exactly 1024
  float nu = expf(nu_log[h]);
  float th = expf(theta_log[h]);
  float r = expf(-nu);
  lam[h]        = r * cosf(th);
  lam[1024 + h] = r * sinf(th);
  float rL = expf(-128.0f * nu);
  lamL[h]        = rL * cosf(128.0f * th);
  lamL[1024 + h] = rL * sinf(128.0f * th);
  gamma[h] = sqrtf(1.0f - expf(-2.0f * nu) + 1e-5f);
}

__global__ void prep_B(const float* __restrict__ B_re, const float* __restrict__ B_im,
                       const float* __restrict__ gamma, unsigned short* __restrict__ Bcat)
{
  int tid = blockIdx.x * 256 + threadIdx.x;  // 2048*1024
  int n = tid >> 10;
  int d = tid & 1023;
  int h = n & 1023;
  float v = (n < 1024 ? B_re[h * 1024 + d] : B_im[h * 1024 + d]) * gamma[h];
  Bcat[tid] = f2bf(v);
}

__global__ void prep_C(const float* __restrict__ C_re, const float* __restrict__ C_im,
                       unsigned short* __restrict__ Ccat)
{
  int tid = blockIdx.x * 256 + threadIdx.x;  // 1024*2048
  int d = tid >> 11;
  int k = tid & 2047;
  float v = (k < 1024) ? C_re[d * 1024 + k] : -C_im[d * 1024 + (k - 1024)];
  Ccat[tid] = f2bf(v);
}

__global__ void conv_inputs(const float* __restrict__ in, unsigned short* __restrict__ outb)
{
  int tid = blockIdx.x * 256 + threadIdx.x;  // 16.7M/4
  float4 v = ((const float4*)in)[tid];
  unsigned lo = (unsigned)f2bf(v.x) | ((unsigned)f2bf(v.y) << 16);
  unsigned hi = (unsigned)f2bf(v.z) | ((unsigned)f2bf(v.w) << 16);
  ((uint2*)outb)[tid] = make_uint2(lo, hi);
}

// ---------------- GEMM (A: [M,K] k-contig, Bt: [N,K] k-contig) ----------------
// 128x128 tile, BK=32, 4 waves (2x2), 16x mfma_f32_16x16x32_bf16 per wave/iter.
// Double-buffered LDS (2 x (8KB A + 8KB B)); one barrier per K-iter; the
// global_load_lds for tile k+1 issue right after the barrier so the next
// barrier's vmcnt(0) drain overlaps this iter's ds_read+MFMA phase.
// XCD-compact swizzle: xcd=id&7 owns m-tiles [xcd*16,(xcd+1)*16) x all
// n-tiles, m-fastest.
// LDS: row r (64B) holds its four 16B k-chunks at positions p storing logical
// chunk p ^ ((r>>1)&3) (bank spread; keeps global_load_lds lane contiguity).

template <int EPI>
__global__ __launch_bounds__(256) void gemm_bt_kernel(
    const unsigned short* __restrict__ A,
    const unsigned short* __restrict__ Bt,
    void* __restrict__ Cout,
    int M, int N, int K,
    const float* __restrict__ skip_in,
    const float* __restrict__ skip_w)
{
  __shared__ unsigned short As[2][128 * 32];
  __shared__ unsigned short Bs[2][128 * 32];

  const int tid  = threadIdx.x;
  const int lane = tid & 63;
  const int wave = tid >> 6;
  const int wm = wave >> 1;
  const int wn = wave & 1;

  // XCD-compact tile assignment (M/128 == 128 assumed: 8 XCDs x 16 m-tiles)
  const int flat    = blockIdx.x;
  const int xcd     = flat & 7;
  const int local   = flat >> 3;
  const int m_tile  = xcd * 16 + (local & 15);
  const int n_tile  = local >> 4;
  const int m0 = m_tile * 128;
  const int n0 = n_tile * 128;

  const int ldr = lane >> 2;   // 0..15: row within a 16-row staging group
  const int pos = lane & 3;    // 16B chunk position within the 64B row
  const int lm  = lane & 15;   // fragment row (A: m, B: n)
  const int q   = lane >> 4;   // fragment k-chunk (k = q*8 + j)

  // Per-thread staging geometry (two rows per thread: half=0/1)
  const int r0 = wave * 32 + ldr;        // rows r0 and r0+16
  const int ca0 = pos ^ ((r0 >> 1) & 3);
  const int r1 = r0 + 16;
  const int ca1 = pos ^ ((r1 >> 1) & 3);

  const unsigned short* gA0 = A  + (size_t)(m0 + r0) * K + ca0 * 8;
  const unsigned short* gA1 = A  + (size_t)(m0 + r1) * K + ca1 * 8;
  const unsigned short* gB0 = Bt + (size_t)(n0 + r0) * K + ca0 * 8;
  const unsigned short* gB1 = Bt + (size_t)(n0 + r1) * K + ca1 * 8;
  const int lofs0 = r0 * 32 + pos * 8;
  const int lofs1 = r1 * 32 + pos * 8;

  floatx4 acc[4][4];
#pragma unroll
  for (int i = 0; i < 4; ++i)
#pragma unroll
    for (int j = 0; j < 4; ++j)
      acc[i][j] = (floatx4){0.f, 0.f, 0.f, 0.f};

  // Preamble: stage tile 0 into buffer 0.
  {
    __builtin_amdgcn_global_load_lds(
        (const __attribute__((address_space(1))) void*)gA0,
        (__attribute__((address_space(3))) void*)&As[0][lofs0], 16, 0, 0);
    __builtin_amdgcn_global_load_lds(
        (const __attribute__((address_space(1))) void*)gA1,
        (__attribute__((address_space(3))) void*)&As[0][lofs1], 16, 0, 0);
    __builtin_amdgcn_global_load_lds(
        (const __attribute__((address_space(1))) void*)gB0,
        (__attribute__((address_space(3))) void*)&Bs[0][lofs0], 16, 0, 0);
    __builtin_amdgcn_global_load_lds(
        (const __attribute__((address_space(1))) void*)gB1,
        (__attribute__((address_space(3))) void*)&Bs[0][lofs1], 16, 0, 0);
  }

  int cur = 0;
  for (int kt = 0; kt < K; kt += 32) {
    // Drains the loads targeting As[cur]/Bs[cur] (issued last iter or in the
    // preamble) and protects the buffer we are about to overwrite (its
    // ds_reads completed before the previous barrier).
    __syncthreads();

    const int nxt = cur ^ 1;
    if (kt + 32 < K) {
      const int ko = kt + 32;
      __builtin_amdgcn_global_load_lds(
          (const __attribute__((address_space(1))) void*)(gA0 + ko),
          (__attribute__((address_space(3))) void*)&As[nxt][lofs0], 16, 0, 0);
      __builtin_amdgcn_global_load_lds(
          (const __attribute__((address_space(1))) void*)(gA1 + ko),
          (__attribute__((address_space(3))) void*)&As[nxt][lofs1], 16, 0, 0);
      __builtin_amdgcn_global_load_lds(
          (const __attribute__((address_space(1))) void*)(gB0 + ko),
          (__attribute__((address_space(3))) void*)&Bs[nxt][lofs0], 16, 0, 0);
      __builtin_amdgcn_global_load_lds(
          (const __attribute__((address_space(1))) void*)(gB1 + ko),
          (__attribute__((address_space(3))) void*)&Bs[nxt][lofs1], 16, 0, 0);
    }

    bf16x8 afrag[4], bfrag[4];
#pragma unroll
    for (int i = 0; i < 4; ++i) {
      const int r = wm * 64 + i * 16 + lm;
      afrag[i] = *reinterpret_cast<const bf16x8*>(&As[cur][r * 32 + (q ^ ((r >> 1) & 3)) * 8]);
    }
#pragma unroll
    for (int j = 0; j < 4; ++j) {
      const int r = wn * 64 + j * 16 + lm;
      bfrag[j] = *reinterpret_cast<const bf16x8*>(&Bs[cur][r * 32 + (q ^ ((r >> 1) & 3)) * 8]);
    }
#pragma unroll
    for (int i = 0; i < 4; ++i)
#pragma unroll
      for (int j = 0; j < 4; ++j)
        acc[i][j] = __builtin_amdgcn_mfma_f32_16x16x32_bf16(afrag[i], bfrag[j], acc[i][j], 0, 0, 0);

    cur = nxt;
  }

  // Epilogue. C/D layout: col = lane&15, row = (lane>>4)*4 + reg.
#pragma unroll
  for (int i = 0; i < 4; ++i) {
#pragma unroll
    for (int j = 0; j < 4; ++j) {
      const int row0 = m0 + wm * 64 + i * 16 + q * 4;
      const int col  = n0 + wn * 64 + j * 16 + lm;
#pragma unroll
      for (int r = 0; r < 4; ++r) {
        const size_t idx = (size_t)(row0 + r) * N + col;
        if (EPI == 0) {
          ((unsigned short*)Cout)[idx] = f2bf(acc[i][j][r]);
        } else {
          ((float*)Cout)[idx] = acc[i][j][r] + skip_in[idx] * skip_w[col];
        }
      }
    }
  }
}

// ---------------- chunked scan over T ----------------
// Bu layout: [(b*4096 + t) * 2048 + h] re-plane (h<1024), +1024 im-plane.
// tid = b*32768 + c*1024 + h  (B=4, C=32 chunks of L=128, H=1024)

__global__ void scan_finals(const unsigned short* __restrict__ Bu,
                            const float* __restrict__ lam,
                            float2* __restrict__ finals)
{
  int tid = blockIdx.x * 256 + threadIdx.x;
  int h = tid & 1023, c = (tid >> 10) & 31, b = tid >> 15;
  float lre = lam[h], lim = lam[1024 + h];
  const unsigned short* p = Bu + ((size_t)(b * 4096 + c * 128) * 2048) + h;
  float yre = 0.f, yim = 0.f;
#pragma unroll 4
  for (int t = 0; t < 128; ++t) {
    float ure = bf2f(p[0]);
    float uim = bf2f(p[1024]);
    float nre = fmaf(lre, yre, fmaf(-lim, yim, ure));
    float nim = fmaf(lre, yim, fmaf(lim, yre, uim));
    yre = nre; yim = nim;
    p += 2048;
  }
  finals[tid] = make_float2(yre, yim);
}

__global__ void scan_carries(const float2* __restrict__ finals,
                             const float* __restrict__ lamL,
                             float2* __restrict__ carry)
{
  int tid = blockIdx.x * 256 + threadIdx.x;  // 4096 = B*H
  int h = tid & 1023, b = tid >> 10;
  float Lre = lamL[h], Lim = lamL[1024 + h];
  float Hre = 0.f, Him = 0.f;
  for (int c = 0; c < 32; ++c) {
    size_t i = ((size_t)(b * 32 + c) << 10) + h;
    carry[i] = make_float2(Hre, Him);   // carry INTO chunk c (H_{c-1})
    float2 f = finals[i];
    float nre = fmaf(Lre, Hre, fmaf(-Lim, Him, f.x));
    float nim = fmaf(Lre, Him, fmaf(Lim, Hre, f.y));
    Hre = nre; Him = nim;
  }
}

__global__ void scan_apply(const float* __restrict__ lam,
                           const float2* __restrict__ carry,
                           unsigned short* __restrict__ Bu)  // in-place -> hs
{
  int tid = blockIdx.x * 256 + threadIdx.x;
  int h = tid & 1023, c = (tid >> 10) & 31, b = tid >> 15;
  float lre = lam[h], lim = lam[1024 + h];
  float2 cv = carry[tid];
  float yre = cv.x, yim = cv.y;
  unsigned short* p = Bu + ((size_t)(b * 4096 + c * 128) * 2048) + h;
#pragma unroll 4
  for (int t = 0; t < 128; ++t) {
    float ure = bf2f(p[0]);
    float uim = bf2f(p[1024]);
    float nre = fmaf(lre, yre, fmaf(-lim, yim, ure));
    float nim = fmaf(lre, yim, fmaf(lim, yre, uim));
    yre = nre; yim = nim;
    p[0]    = f2bf(yre);
    p[1024] = f2bf(yim);
    p += 2048;
  }
}

// ---------------- launch ----------------

extern "C" void kernel_launch(void* const* d_in, const int* in_sizes, int n_in,
                              void* d_out, int out_size, void* d_ws, size_t ws_size,
                              hipStream_t stream)
{
  const float* inputs    = (const float*)d_in[0];
  const float* nu_log    = (const float*)d_in[1];
  const float* theta_log = (const float*)d_in[2];
  const float* B_re      = (const float*)d_in[3];
  const float* B_im      = (const float*)d_in[4];
  const float* C_re      = (const float*)d_in[5];
  const float* C_im      = (const float*)d_in[6];
  const float* D_skip    = (const float*)d_in[7];
  float* out = (float*)d_out;

  char* ws = (char*)d_ws;
  float* lam   = (float*)ws;            // 2048 f32
  float* lamL  = lam + 2048;            // 2048 f32
  float* gamma = lamL + 2048;           // 1024 f32
  unsigned short* inp_bf = (unsigned short*)(ws + (1 << 16));       // 16384x1024 bf16
  unsigned short* Bcat   = inp_bf + (size_t)16384 * 1024;           // 2048x1024
  unsigned short* Ccat   = Bcat   + (size_t)2048 * 1024;            // 1024x2048
  unsigned short* Bu     = Ccat   + (size_t)1024 * 2048;            // 16384x2048 (re|im), becomes hs in place
  float2* finals = (float2*)(Bu + (size_t)16384 * 2048);            // 131072
  float2* carry  = finals + 131072;                                 // 131072
  // total ws use ~111 MB

  prep_params<<<4,    256, 0, stream>>>(nu_log, theta_log, lam, lamL, gamma);
  prep_B     <<<8192, 256, 0, stream>>>(B_re, B_im, gamma, Bcat);
  prep_C     <<<8192, 256, 0, stream>>>(C_re, C_im, Ccat);
  conv_inputs<<<16384,256, 0, stream>>>(inputs, inp_bf);

  // GEMM1: Bu[bt, n] = inputs @ Bcat^T   (M=16384, N=2048, K=1024)
  gemm_bt_kernel<0><<<2048, 256, 0, stream>>>(
      inp_bf, Bcat, Bu, 16384, 2048, 1024, nullptr, nullptr);

  scan_finals <<<512, 256, 0, stream>>>(Bu, lam, finals);
  scan_carries<<<16,  256, 0, stream>>>(finals, lamL, carry);
  scan_apply  <<<512, 256, 0, stream>>>(lam, carry, Bu);   // Bu -> hs in place

  // GEMM2: out[bt, d] = hs @ Ccat^T + inputs * D_skip  (M=16384, N=1024, K=2048)
  gemm_bt_kernel<1><<<1024, 256, 0, stream>>>(
      Bu, Ccat, out, 16384, 1024, 2048, inputs, D_skip);
}